// Round 11
// baseline (258.116 us; speedup 1.0000x reference)
//
#include <hip/hip_runtime.h>

// OneDilate: out[b,c,i,j] = 50 - 0.5 * sum_{10x10 clamped window} x
// Separable, V-only-LDS, forced-MLP kernel.
//  Rounds 6-9 invariant: 60-65us across 4 structures while VALU/LDS work
//  varied 3x -> wall is average outstanding load bytes (Little's law), not
//  any pipe. r9's VGPR=28 proves the compiler serialized the 11-load burst
//  ~4-deep. This round: t[11] array + sched_barrier(0) forces all 11 loads
//  issued before any consume (44 live VGPRs, cap 128 via (512,4));
//  512-thr blocks x 6144 = finer phase interleave; float4 stores (4x fewer
//  store insts); wave-uniform interior fast path (no row clamps).

#define IMG 512
#define OUTW 511
#define KS 10
#define MEAN 4
#define SUBB 8                   // output rows per block
#define ROWF4 (IMG / 4)          // 128 float4 per row
#define NTHREADS 512
#define NBANDS (IMG / SUBB)      // 64
#define NIMG 96                  // 32 * 3 images
#define NWG (NBANDS * NIMG)      // 6144 (divisible by 8 XCDs)
#define CPX (NWG / 8)            // 768 per XCD chunk

__device__ __forceinline__ float4 f4add(float4 a, float4 b) {
    return make_float4(a.x + b.x, a.y + b.y, a.z + b.z, a.w + b.w);
}

__global__ __launch_bounds__(NTHREADS, 4) void onedilate_kernel(
    const float* __restrict__ x, float* __restrict__ out)
{
    __shared__ float Vb[SUBB * IMG];   // 16 KiB: 8 rows of vertical 10-sums

    // Bijective XCD-aware swizzle: each XCD owns a contiguous chunk of
    // (band, image); adjacent bands of one image share 9 halo rows in L2.
    const int lin = blockIdx.y * NBANDS + blockIdx.x;
    const int swz = (lin & 7) * CPX + (lin >> 3);
    const int bx  = swz & (NBANDS - 1);  // band
    const int bc  = swz >> 6;            // image (NBANDS == 64)

    const int tid = threadIdx.x;
    const int jc  = tid & (ROWF4 - 1);   // float4 col group 0..127
    const int rg  = tid >> 7;            // row group 0..3 (2 rows each)
    const int rb  = bx * SUBB;           // first output row of this band

    const float* __restrict__ xim = x + (size_t)bc * (IMG * IMG);
    float* __restrict__ oim = out + (size_t)bc * (OUTW * OUTW);

    // ---------- B1: vertical 10-sums, global -> LDS ----------
    // Thread covers V rows 2rg, 2rg+1 (abs rows i0, i0+1):
    //   V[i] = sum_{d=-4..5} x[clamp(i+d)]; needs x rows i0-4 .. i0+6.
    {
        const int i0 = rb + 2 * rg;
        const float* cp = xim + jc * 4;
        float4 t[11];
        // Block reads rows rb-4 .. rb+12: interior iff rb>=4 && rb+12<=511.
        if (rb >= MEAN && rb + 12 <= IMG - 1) {   // wave-uniform (62/64 bands)
            const float* p = cp + (size_t)(i0 - MEAN) * IMG;
#pragma unroll
            for (int k = 0; k < 11; ++k)
                t[k] = *(const float4*)(p + (size_t)k * IMG);
        } else {
#pragma unroll
            for (int k = 0; k < 11; ++k) {
                const int ri = min(max(i0 - MEAN + k, 0), IMG - 1);
                t[k] = *(const float4*)(cp + (size_t)ri * IMG);
            }
        }
        // Force all 11 loads issued before any consumption (defeats the
        // scheduler's pressure-minimizing serialization seen in r9 VGPR=28).
        __builtin_amdgcn_sched_barrier(0);

        const float4 s01 = f4add(t[0], t[1]), s23 = f4add(t[2], t[3]);
        const float4 s45 = f4add(t[4], t[5]), s67 = f4add(t[6], t[7]);
        const float4 s89 = f4add(t[8], t[9]);
        const float4 v0 = f4add(f4add(f4add(s01, s23), f4add(s45, s67)), s89);
        const float4 v1 = make_float4(
            v0.x + t[10].x - t[0].x, v0.y + t[10].y - t[0].y,
            v0.z + t[10].z - t[0].z, v0.w + t[10].w - t[0].w);
        float4* Vv = (float4*)Vb;
        Vv[(2 * rg + 0) * ROWF4 + jc] = v0;
        Vv[(2 * rg + 1) * ROWF4 + jc] = v1;
    }
    __syncthreads();

    // ---------- B2: horizontal 10-sums, LDS -> out ----------
    const int cbase = 4 * jc;
    const int bl0 = max(cbase - 4, 0);        // only jc=0 OOB-low
    const int bl2 = min(cbase + 4, IMG - 4);  // only jc=127 OOB-high
    const int bl3 = min(cbase + 8, IMG - 4);  // jc=126,127 OOB-high
    const bool lo0 = (cbase - 4 < 0);
    const bool hi2 = (cbase + 4 > IMG - 4);
    const bool hi3 = (cbase + 8 > IMG - 4);

#pragma unroll
    for (int k = 0; k < 2; ++k) {
        const int r = 2 * rg + k;             // local V row
        const float* rp = Vb + r * IMG;
        float4 v0 = *(const float4*)(rp + bl0);
        float4 v1 = *(const float4*)(rp + cbase);
        float4 v2 = *(const float4*)(rp + bl2);
        float4 v3 = *(const float4*)(rp + bl3);
        if (lo0) v0 = make_float4(v0.x, v0.x, v0.x, v0.x);  // col 0 replicate
        if (hi2) v2 = make_float4(v2.w, v2.w, v2.w, v2.w);  // col 511 replicate
        const float w12 = hi3 ? v3.w : v3.x;                // col min(4jc+8,511)

        const float S = ((v0.x + v0.y) + (v0.z + v0.w))
                      + ((v1.x + v1.y) + (v1.z + v1.w))
                      + (v2.x + v2.y);
        const float d1  = v2.z - v0.x;
        const float d2  = v2.w - v0.y;
        const float d3  = w12  - v0.z;
        const float d12 = d1 + d2;

        const int i = rb + r;
        if (i < OUTW) {                       // only band 63's row 7 fails
            float* op = oim + (size_t)i * OUTW + cbase;
            const float4 o = make_float4(fmaf(S, -0.5f, 50.0f),
                                         fmaf(S + d1, -0.5f, 50.0f),
                                         fmaf(S + d12, -0.5f, 50.0f),
                                         fmaf(S + (d12 + d3), -0.5f, 50.0f));
            if (cbase + 3 < OUTW) {
                *(float4*)op = o;             // dwordx4, 4B-aligned (HW-legal)
            } else {                          // jc=127: cols 508..510 only
                op[0] = o.x;
                op[1] = o.y;
                op[2] = o.z;
            }
        }
    }
}

extern "C" void kernel_launch(void* const* d_in, const int* in_sizes, int n_in,
                              void* d_out, int out_size, void* d_ws, size_t ws_size,
                              hipStream_t stream) {
    const float* x = (const float*)d_in[0];
    float* out = (float*)d_out;

    dim3 block(NTHREADS, 1, 1);
    dim3 grid(NBANDS, NIMG, 1);   // 64 x 96 = 6144 blocks
    onedilate_kernel<<<grid, block, 0, stream>>>(x, out);
}

// Round 14
// 185.406 us; speedup vs baseline: 1.3922x; 1.3922x over previous
//
#include <hip/hip_runtime.h>

// OneDilate: out[b,c,i,j] = 50 - 0.5 * sum_{10x10 clamped window} x
// Barrier-free dataflow kernel: NO LDS, NO __syncthreads, no waitcnt asm.
//  Rounds 6-11: five bulk-synchronous structures all pinned at 60-65us with
//  every pipe <40% busy -- the shared feature is phase-correlated waves
//  (load burst -> drain -> compute -> store, all waves together). r11
//  falsified forced per-wave MLP (143us). This kernel removes synchronization
//  entirely: each wave independently owns 4 output rows x 512 cols; lane
//  holds 8 cols; vertical 10-sums in registers from 13 clamped row loads
//  (26 independent float4s, compiler-scheduled); horizontal 10-sums get the
//  4-left/5-right column halo via __shfl_up/__shfl_down(1) (delta-1
//  bpermute, conflict-free) instead of an LDS round-trip. Waves drift out
//  of phase -> loads/compute/stores interleave continuously.

#define IMG 512
#define OUTW 511
#define MEAN 4
#define ROWSPW 4                 // output rows per wave
#define NTHREADS 256             // 4 waves per block
#define ROWSPB 16                // rows per block
#define NBANDS (IMG / ROWSPB)    // 32
#define NIMG 96                  // 32 * 3 images
#define NWG (NBANDS * NIMG)      // 3072 (divisible by 8 XCDs)
#define CPX (NWG / 8)            // 384 per XCD chunk

__device__ __forceinline__ float4 f4add(float4 a, float4 b) {
    return make_float4(a.x + b.x, a.y + b.y, a.z + b.z, a.w + b.w);
}
__device__ __forceinline__ float4 f4slide(float4 v, float4 add, float4 sub) {
    return make_float4(v.x + add.x - sub.x, v.y + add.y - sub.y,
                       v.z + add.z - sub.z, v.w + add.w - sub.w);
}
__device__ __forceinline__ float4 shflup1(float4 v) {
    return make_float4(__shfl_up(v.x, 1, 64), __shfl_up(v.y, 1, 64),
                       __shfl_up(v.z, 1, 64), __shfl_up(v.w, 1, 64));
}
__device__ __forceinline__ float4 shfldn1(float4 v) {
    return make_float4(__shfl_down(v.x, 1, 64), __shfl_down(v.y, 1, 64),
                       __shfl_down(v.z, 1, 64), __shfl_down(v.w, 1, 64));
}

__global__ __launch_bounds__(NTHREADS) void onedilate_kernel(
    const float* __restrict__ x, float* __restrict__ out)
{
    // Bijective XCD-aware swizzle: each XCD owns a contiguous chunk of
    // (band, image); adjacent bands of one image share halo rows in L2.
    const int lin = blockIdx.y * NBANDS + blockIdx.x;
    const int swz = (lin & 7) * CPX + (lin >> 3);
    const int bx  = swz & (NBANDS - 1);  // band
    const int bc  = swz >> 5;            // image (NBANDS == 32)

    const int tid  = threadIdx.x;
    const int lane = tid & 63;
    const int wid  = tid >> 6;           // wave id 0..3 (wave-uniform)
    const int i0   = bx * ROWSPB + wid * ROWSPW;  // first output row (uniform)

    const float* __restrict__ xim = x + (size_t)bc * (IMG * IMG);
    float* __restrict__ oim = out + (size_t)bc * (OUTW * OUTW);
    const float* cp = xim + lane * 8;    // lane's column base (8 cols)

    // ---- loads: 13 clamped rows x 2 float4 (26 independent loads) ----
    float4 a[13], b[13];
#pragma unroll
    for (int k = 0; k < 13; ++k) {
        const int ri = min(max(i0 - MEAN + k, 0), IMG - 1);  // SALU (uniform)
        const float* rp = cp + (size_t)ri * IMG;
        a[k] = *(const float4*)rp;
        b[k] = *(const float4*)(rp + 4);
    }

    // ---- vertical 10-sums (tree for row 0, slide for rows 1..3) ----
    float4 va = f4add(f4add(f4add(f4add(a[0], a[1]), f4add(a[2], a[3])),
                            f4add(f4add(a[4], a[5]), f4add(a[6], a[7]))),
                      f4add(a[8], a[9]));
    float4 vb = f4add(f4add(f4add(f4add(b[0], b[1]), f4add(b[2], b[3])),
                            f4add(f4add(b[4], b[5]), f4add(b[6], b[7]))),
                      f4add(b[8], b[9]));

#pragma unroll
    for (int r = 0; r < ROWSPW; ++r) {
        if (r > 0) {
            va = f4slide(va, a[9 + r], a[r - 1]);
            vb = f4slide(vb, b[9 + r], b[r - 1]);
        }
        // ---- horizontal: halo via delta-1 shuffles ----
        // W[0..16] = V[c0-4 .. c0+12]:
        //   W0..3 = left lane's vb | W4..7 = va | W8..11 = vb
        //   W12..15 = right lane's va | W16 = right lane's vb.x
        float4 L = shflup1(vb);
        float4 R = shfldn1(va);
        float  rx = __shfl_down(vb.x, 1, 64);
        if (lane == 0)  L = make_float4(va.x, va.x, va.x, va.x);   // col 0 repl
        if (lane == 63) { R = make_float4(vb.w, vb.w, vb.w, vb.w); // col 511
                          rx = vb.w; }

        const float S = ((L.x + L.y) + (L.z + L.w))
                      + ((va.x + va.y) + (va.z + va.w))
                      + (vb.x + vb.y);                 // H[c0] = sum W0..W9
        const float h0 = S;
        const float h1 = h0 + vb.z - L.x;
        const float h2 = h1 + vb.w - L.y;
        const float h3 = h2 + R.x  - L.z;
        const float h4 = h3 + R.y  - L.w;
        const float h5 = h4 + R.z  - va.x;
        const float h6 = h5 + R.w  - va.y;
        const float h7 = h6 + rx   - va.z;

        const int i = i0 + r;
        if (i < OUTW) {                   // only band 31 / wave 3 / r=3 fails
            float* op = oim + (size_t)i * OUTW + lane * 8;
            *(float4*)op = make_float4(fmaf(h0, -0.5f, 50.0f),
                                       fmaf(h1, -0.5f, 50.0f),
                                       fmaf(h2, -0.5f, 50.0f),
                                       fmaf(h3, -0.5f, 50.0f));
            if (lane < 63) {              // cols c0+4..c0+7 <= 510
                *(float4*)(op + 4) = make_float4(fmaf(h4, -0.5f, 50.0f),
                                                 fmaf(h5, -0.5f, 50.0f),
                                                 fmaf(h6, -0.5f, 50.0f),
                                                 fmaf(h7, -0.5f, 50.0f));
            } else {                      // lane 63: cols 508..510 only
                op[4] = fmaf(h4, -0.5f, 50.0f);
                op[5] = fmaf(h5, -0.5f, 50.0f);
                op[6] = fmaf(h6, -0.5f, 50.0f);
            }
        }
    }
}

extern "C" void kernel_launch(void* const* d_in, const int* in_sizes, int n_in,
                              void* d_out, int out_size, void* d_ws, size_t ws_size,
                              hipStream_t stream) {
    const float* x = (const float*)d_in[0];
    float* out = (float*)d_out;

    dim3 block(NTHREADS, 1, 1);
    dim3 grid(NBANDS, NIMG, 1);   // 32 x 96 = 3072 blocks
    onedilate_kernel<<<grid, block, 0, stream>>>(x, out);
}

// Round 15
// 177.520 us; speedup vs baseline: 1.4540x; 1.0444x over previous
//
#include <hip/hip_runtime.h>

// OneDilate: out[b,c,i,j] = 50 - 0.5 * sum_{10x10 clamped window} x
// r6 structure (one-shot blocks, global_load_lds staging, fused phase B) at
// DOUBLE residency: SUBB 16->8, LDS 50->34KB => 4 blocks/CU (vs 3), 2048
// threads/CU (cap). Rounds 6-14: seven structures, 60-68us invariant; r6
// (cross-block stage<->compute overlap, 3-deep) is best. Only untested
// lever on it: residency depth. Phase B: 2 output rows/thread, 11-row
// streaming window with 2 accumulators (r6's proven shape, lower VGPR).

#define IMG 512
#define OUTW 511
#define KS 10
#define MEAN 4
#define SUBB 8                   // output rows per block
#define TS (SUBB + KS - 1)       // 17 staged rows
#define ROWF4 (IMG / 4)          // 128 float4 per row
#define NF4 (TS * ROWF4)         // 2176 float4 = 34 KiB LDS
#define NTHREADS 512
#define NBANDS (IMG / SUBB)      // 64
#define NIMG 96                  // 32 * 3 images
#define NWG (NBANDS * NIMG)      // 6144 (divisible by 8 XCDs)
#define CPX (NWG / 8)            // 768 per XCD chunk

__global__ __launch_bounds__(NTHREADS) void onedilate_kernel(
    const float* __restrict__ x, float* __restrict__ out)
{
    __shared__ float smemf[TS * IMG];   // 34816 B -> 4 blocks/CU

    // Bijective XCD-aware swizzle: each XCD owns a contiguous chunk of
    // (band, image); adjacent bands of one image share halo rows in L2.
    const int lin = blockIdx.y * NBANDS + blockIdx.x;
    const int swz = (lin & 7) * CPX + (lin >> 3);
    const int bx  = swz & (NBANDS - 1);  // band
    const int bc  = swz >> 6;            // image (NBANDS == 64)

    const int tid = threadIdx.x;
    const int rb  = bx * SUBB;           // first output row of this band

    const float* __restrict__ xim = x + (size_t)bc * (IMG * IMG);
    float* __restrict__ oim = out + (size_t)bc * (OUTW * OUTW);

    // ---------------- Phase A: async stage tile into LDS ----------------
    // idx -> (row r = idx>>7, colgroup c4 = idx&127); row clamped.
    // LDS byte offset = idx*16: linear in tid (HW wave-base + lane*16, m104).
#define STAGE1(idx_)                                                       \
    {                                                                      \
        const int r_  = (idx_) >> 7;                                       \
        const int c4_ = (idx_) & (ROWF4 - 1);                              \
        const int ri_ = min(max(rb - MEAN + r_, 0), IMG - 1);              \
        __builtin_amdgcn_global_load_lds(                                  \
            (const __attribute__((address_space(1))) void*)                \
                (xim + (size_t)ri_ * IMG + c4_ * 4),                       \
            (__attribute__((address_space(3))) void*)(smemf + (idx_) * 4), \
            16, 0, 0);                                                     \
    }
#pragma unroll
    for (int k = 0; k < 4; ++k) STAGE1(k * NTHREADS + tid)
    if (tid < (NF4 - 4 * NTHREADS)) STAGE1(4 * NTHREADS + tid)  // waves 0-1 full
#undef STAGE1
    __syncthreads();   // drains the global_load_lds queue

    // ---------------- Phase B: fused V+H sums from LDS ----------------
    const int j  = tid & 127;             // col group: output cols 4j..4j+3
    const int rg = tid >> 7;              // row group 0..3 (2 rows each)
    const int cbase = 4 * j;
    const int bl0 = max(cbase - 4, 0);        // only j=0 OOB-low
    const int bl2 = min(cbase + 4, IMG - 4);  // only j=127 OOB-high
    const int bl3 = min(cbase + 8, IMG - 4);  // j=126,127 OOB-high
    const bool lo0 = (cbase - 4 < 0);
    const bool hi2 = (cbase + 4 > IMG - 4);
    const bool hi3 = (cbase + 8 > IMG - 4);

    // Thread covers output rows i0, i0+1 <- local staged rows 2rg..2rg+10
    // (window [k..k+9] for k=0,1). Stream 11 rows; accumulate H into A0/A1.
    const int base = 2 * rg;
    float4 A0 = make_float4(0.f, 0.f, 0.f, 0.f);
    float4 A1 = A0;

#pragma unroll
    for (int k = 0; k < 11; ++k) {
        const float* rp = smemf + (base + k) * IMG;
        float4 v0 = *(const float4*)(rp + bl0);
        float4 v1 = *(const float4*)(rp + cbase);
        float4 v2 = *(const float4*)(rp + bl2);
        float4 v3 = *(const float4*)(rp + bl3);
        if (lo0) v0 = make_float4(v0.x, v0.x, v0.x, v0.x);  // col 0 replicate
        if (hi2) v2 = make_float4(v2.w, v2.w, v2.w, v2.w);  // col 511 replicate
        const float w12 = hi3 ? v3.w : v3.x;                // col min(4j+8,511)

        // Horizontal 10-sums: tree sum + parallel sliding diffs (proven).
        const float S = ((v0.x + v0.y) + (v0.z + v0.w))
                      + ((v1.x + v1.y) + (v1.z + v1.w))
                      + (v2.x + v2.y);
        const float d1  = v2.z - v0.x;
        const float d2  = v2.w - v0.y;
        const float d3  = w12  - v0.z;
        const float d12 = d1 + d2;
        float4 H;
        H.x = S;
        H.y = S + d1;
        H.z = S + d12;
        H.w = S + (d12 + d3);

        // Vertical windows (static after unroll): A0 sums k in [0,9],
        // A1 sums k in [1,10].
        if (k <= 9) { A0.x += H.x; A0.y += H.y; A0.z += H.z; A0.w += H.w; }
        if (k >= 1) { A1.x += H.x; A1.y += H.y; A1.z += H.z; A1.w += H.w; }
    }

    const int i0 = rb + 2 * rg;
#define STORE(ro_, A_)                                                     \
    { const int i = i0 + (ro_);                                            \
      if (i < OUTW) {                    /* only band 63 / rg 3 / ro 1 */  \
          float* op = oim + (size_t)i * OUTW + cbase;                      \
          const float4 o = make_float4(fmaf(A_.x, -0.5f, 50.0f),           \
                                       fmaf(A_.y, -0.5f, 50.0f),           \
                                       fmaf(A_.z, -0.5f, 50.0f),           \
                                       fmaf(A_.w, -0.5f, 50.0f));          \
          if (cbase + 3 < OUTW) {                                          \
              *(float4*)op = o;          /* dwordx4, 4B-aligned */         \
          } else {                       /* j=127: cols 508..510 */        \
              op[0] = o.x; op[1] = o.y; op[2] = o.z;                       \
          }                                                                \
      } }
    STORE(0, A0)
    STORE(1, A1)
#undef STORE
}

extern "C" void kernel_launch(void* const* d_in, const int* in_sizes, int n_in,
                              void* d_out, int out_size, void* d_ws, size_t ws_size,
                              hipStream_t stream) {
    const float* x = (const float*)d_in[0];
    float* out = (float*)d_out;

    dim3 block(NTHREADS, 1, 1);
    dim3 grid(NBANDS, NIMG, 1);   // 64 x 96 = 6144 blocks
    onedilate_kernel<<<grid, block, 0, stream>>>(x, out);
}